// Round 1
// baseline (873.317 us; speedup 1.0000x reference)
//
#include <hip/hip_runtime.h>
#include <math.h>

namespace {

constexpr int kB  = 8,  kS  = 64, kC  = 16, kH = 64, kW = 64;
constexpr int kHC = 32, kHP = 62, kWP = 62;
constexpr int kThreads = 256;

// Block layout: 256 threads
//   colg = tid & 15   -> 16 groups of 4 output cols (c0 = colg*4)
//   ocg  = (tid>>4)&7 -> 8 groups of 4 channel-pairs (g0 = ocg*4; gate ch g0+j, hidden ch g0+32+j)
//   rloc = tid >> 7   -> 2 output rows per block
// Grid: (31 row-tiles) x (8 batch). Block persists over s = 0..63, h-state in registers.
__global__ __launch_bounds__(kThreads, 1)
void fused_conv_gru(const float* __restrict__ x,
                    const float* __restrict__ wgt,
                    const float* __restrict__ bias,
                    float* __restrict__ out)
{
    __shared__ float wlds[144 * 64];     // [ic*9 + ky*3 + kx][oc]
    __shared__ float xlds[kC * 4 * 68];  // [ic][rr(4)][c], row pitch 68 (16B-aligned, +halo pad)

    const int tid  = threadIdx.x;
    const int tile = blockIdx.x;     // 0..30
    const int bb   = blockIdx.y;     // 0..7
    const int r0   = tile * 2;

    // stage weights once: wlds[(ic*9+tap)*64 + oc] = W[oc][ic][tap]
    for (int i = tid; i < 144 * 64; i += kThreads) {
        const int oc = i & 63, rest = i >> 6;
        wlds[i] = wgt[oc * 144 + rest];
    }

    const int colg = tid & 15;
    const int ocg  = (tid >> 4) & 7;
    const int rloc = tid >> 7;
    const int g0   = ocg * 4;
    const int c0   = colg * 4;
    const int row  = r0 + rloc;

    float bg[4], bh[4];
    #pragma unroll
    for (int j = 0; j < 4; ++j) { bg[j] = bias[g0 + j]; bh[j] = bias[kHC + g0 + j]; }

    float h[4][4];
    #pragma unroll
    for (int p = 0; p < 4; ++p)
        #pragma unroll
        for (int j = 0; j < 4; ++j) h[p][j] = 0.5f;

    const float* xb = x + (size_t)bb * kS * kC * kH * kW;
    float* outh = out + (size_t)bb * kS * kHC * kHP * kWP;
    float* outf = out + (size_t)kB * kS * kHC * kHP * kWP + (size_t)bb * kHC * kHP * kWP;

    __syncthreads();

    for (int s = 0; s < kS; ++s) {
        // ---- stage x tile: rows r0..r0+3 (contiguous in h within each ic plane), 64 cols, 16 ch
        const float* xs = xb + (size_t)s * kC * kH * kW + r0 * kW;
        #pragma unroll
        for (int v = 0; v < 4; ++v) {
            const int li  = v * 1024 + tid * 4;   // 0..4095, coalesced float4
            const int ic  = li >> 8;
            const int off = li & 255;             // rr*64 + c
            const int rr  = off >> 6;
            const int c   = off & 63;
            const float4 val = *reinterpret_cast<const float4*>(xs + ic * (kH * kW) + off);
            *reinterpret_cast<float4*>(&xlds[(ic * 4 + rr) * 68 + c]) = val;
        }
        __syncthreads();

        // ---- conv accumulate: 4 px x (4 gate + 4 hidden) channels per thread
        float ag[4][4] = {{0.f}};
        float ah[4][4] = {{0.f}};
        #pragma unroll 4
        for (int ic = 0; ic < kC; ++ic) {
            #pragma unroll
            for (int ky = 0; ky < 3; ++ky) {
                const float* xr = &xlds[(ic * 4 + rloc + ky) * 68 + c0];
                float xrow[6];
                #pragma unroll
                for (int u = 0; u < 6; ++u) xrow[u] = xr[u];
                #pragma unroll
                for (int kx = 0; kx < 3; ++kx) {
                    const float* wrow = &wlds[(ic * 9 + ky * 3 + kx) * 64];
                    float wg[4], wh[4];
                    #pragma unroll
                    for (int j = 0; j < 4; ++j) {
                        wg[j] = wrow[g0 + j];
                        wh[j] = wrow[kHC + g0 + j];
                    }
                    #pragma unroll
                    for (int p = 0; p < 4; ++p) {
                        const float xv = xrow[p + kx];
                        #pragma unroll
                        for (int j = 0; j < 4; ++j) {
                            ag[p][j] = fmaf(xv, wg[j], ag[p][j]);
                            ah[p][j] = fmaf(xv, wh[j], ah[p][j]);
                        }
                    }
                }
            }
        }

        // ---- gating + recurrence + store
        float* os = outh + (size_t)s * kHC * kHP * kWP;
        #pragma unroll
        for (int j = 0; j < 4; ++j) {
            #pragma unroll
            for (int p = 0; p < 4; ++p) {
                const float gate = ag[p][j] + bg[j];
                const float hid  = ah[p][j] + bh[j];
                const float z    = 1.f / (1.f + __expf(-gate));
                const float gv   = (hid >= 0.f) ? (hid + 0.5f)
                                                : 1.f / (1.f + __expf(-hid));
                const float hn   = (1.f - z) * h[p][j] + z * gv;
                h[p][j] = hn;
                const int c = c0 + p;
                if (c < kWP) {
                    const int o = ((g0 + j) * kHP + row) * kWP + c;
                    os[o] = hn;
                    if (s == kS - 1) outf[o] = hn;
                }
            }
        }
        __syncthreads();
    }
}

} // namespace

extern "C" void kernel_launch(void* const* d_in, const int* in_sizes, int n_in,
                              void* d_out, int out_size, void* d_ws, size_t ws_size,
                              hipStream_t stream)
{
    const float* x  = (const float*)d_in[0];
    const float* Wt = (const float*)d_in[1];
    const float* b  = (const float*)d_in[2];
    float* out = (float*)d_out;

    dim3 grid(31, 8);
    fused_conv_gru<<<grid, dim3(kThreads), 0, stream>>>(x, Wt, b, out);
}

// Round 2
// 486.901 us; speedup vs baseline: 1.7936x; 1.7936x over previous
//
#include <hip/hip_runtime.h>
#include <hip/hip_bf16.h>

namespace {

typedef __attribute__((ext_vector_type(8))) short bf16x8;
typedef __attribute__((ext_vector_type(4))) float f32x4;

constexpr int kB = 8, kS = 64, kC = 16, kH = 64, kW = 64;
constexpr int kHC = 32, kHP = 62, kWP = 62;
constexpr int kPlane = kH * kW * kC;          // 65536 elements per (b,s) in x_t
constexpr int kPix = kHP * kWP;               // 3844
constexpr int kKpad = 160;                    // K=144 padded to 160

// ---------------- pre-pass 1: x [b][s][ic][h][w] fp32 -> x_t [b][s][h][w][ic] bf16
__global__ __launch_bounds__(256)
void transpose_x(const float* __restrict__ x, __hip_bfloat16* __restrict__ xt)
{
    const size_t idx = (size_t)blockIdx.x * 256 + threadIdx.x;   // 0 .. 8*64*4096-1
    const size_t bs  = idx >> 12;
    const int    px  = (int)(idx & 4095);
    const float* src = x + bs * (size_t)(kC * kH * kW) + px;

    float v[16];
    #pragma unroll
    for (int ic = 0; ic < 16; ++ic) v[ic] = src[ic * (kH * kW)];  // coalesced across lanes

    union { unsigned short u[16]; uint4 q[2]; } p;
    #pragma unroll
    for (int ic = 0; ic < 16; ++ic) {
        __hip_bfloat16 hb = __float2bfloat16(v[ic]);
        p.u[ic] = *reinterpret_cast<unsigned short*>(&hb);
    }
    uint4* dst = reinterpret_cast<uint4*>(xt + idx * 16);
    dst[0] = p.q[0];
    dst[1] = p.q[1];
}

// ---------------- pre-pass 2: W [oc][ic][3][3] fp32 -> Wk [oc][k] bf16, k = ky*48+kx*16+ic, pad to 160
__global__ __launch_bounds__(256)
void reorder_w(const float* __restrict__ wgt, __hip_bfloat16* __restrict__ wk)
{
    const int i = blockIdx.x * 256 + threadIdx.x;
    if (i >= 64 * kKpad) return;
    const int oc = i / kKpad, k = i % kKpad;
    float val = 0.f;
    if (k < 144) {
        const int ky = k / 48, r = k % 48, kx = r / 16, ic = r % 16;
        val = wgt[oc * 144 + ic * 9 + ky * 3 + kx];
    }
    wk[i] = __float2bfloat16(val);
}

// ---------------- main: fused MFMA conv + GRU scan. One wave = (b, py, 16-px tile), loops s.
__global__ __launch_bounds__(256, 2)
void conv_gru_mfma(const __hip_bfloat16* __restrict__ xt,
                   const __hip_bfloat16* __restrict__ wk,
                   const float* __restrict__ bias,
                   float* __restrict__ out)
{
    const int tid  = threadIdx.x;
    const int lane = tid & 63;
    const int wv   = tid >> 6;          // 0..3 -> px tile
    const int py   = blockIdx.x;        // 0..61
    const int b    = blockIdx.y;        // 0..7
    const int px0  = wv * 16;
    const int n    = lane & 15;         // A row m / B col n / D col n
    const int q    = lane >> 4;         // k-quad / D row group

    // ---- weight fragments: wf[t][c], t = oc-tile (0..3), c = K-chunk (0..4). 80 VGPRs, loaded once.
    bf16x8 wf[4][5];
    #pragma unroll
    for (int t = 0; t < 4; ++t)
        #pragma unroll
        for (int c = 0; c < 5; ++c)
            wf[t][c] = *reinterpret_cast<const bf16x8*>(
                wk + (t * 16 + n) * kKpad + c * 32 + q * 8);

    // ---- per-lane A-fragment element offsets within one (b,s) plane (constant over s)
    const int m = n;                                   // A row = pixel within tile
    const int px_eff = (px0 + m > 61) ? 61 : (px0 + m); // clamp keeps all reads in-plane
    int aoff[5];
    #pragma unroll
    for (int c = 0; c < 5; ++c) {
        int k = c * 32 + q * 8;
        int ky, off;
        if (k >= 144) { ky = 2; off = 32; }            // pad chunk: W=0, address harmless
        else          { ky = k / 48; off = k % 48; }
        aoff[c] = (py + ky) * (kW * kC) + px_eff * kC + off;
    }

    const __hip_bfloat16* xb = xt + (size_t)b * kS * kPlane;

    const float bg[2] = { bias[n],      bias[16 + n] };
    const float bh[2] = { bias[32 + n], bias[48 + n] };

    float h[2][4];
    #pragma unroll
    for (int t = 0; t < 2; ++t)
        #pragma unroll
        for (int r = 0; r < 4; ++r) h[t][r] = 0.5f;

    float* outh = out + (size_t)b * kS * kHC * kPix;
    float* outf = out + (size_t)kB * kS * kHC * kPix + (size_t)b * kHC * kPix;

    const int px_st = px0 + q * 4;                      // store base col (4 px per lane)
    const bool full4 = (px_st + 3 <= 61);

    for (int s = 0; s < kS; ++s) {
        const __hip_bfloat16* xs = xb + (size_t)s * kPlane;

        bf16x8 af[5];
        #pragma unroll
        for (int c = 0; c < 5; ++c)
            af[c] = *reinterpret_cast<const bf16x8*>(xs + aoff[c]);

        f32x4 acc[4];
        #pragma unroll
        for (int t = 0; t < 4; ++t) acc[t] = (f32x4){0.f, 0.f, 0.f, 0.f};

        #pragma unroll
        for (int c = 0; c < 5; ++c)
            #pragma unroll
            for (int t = 0; t < 4; ++t)
                acc[t] = __builtin_amdgcn_mfma_f32_16x16x32_bf16(af[c], wf[t][c], acc[t], 0, 0, 0);

        // ---- gating + recurrence + store (hidden tiles t+2 pair with gate tiles t, same lane)
        float* os = outh + (size_t)s * kHC * kPix + py * kWP;
        #pragma unroll
        for (int t = 0; t < 2; ++t) {
            #pragma unroll
            for (int r = 0; r < 4; ++r) {
                const float gate = acc[t][r]     + bg[t];
                const float hid  = acc[t + 2][r] + bh[t];
                const float z    = 1.f / (1.f + __expf(-gate));
                const float gv   = (hid >= 0.f) ? (hid + 0.5f)
                                                : 1.f / (1.f + __expf(-hid));
                h[t][r] = (1.f - z) * h[t][r] + z * gv;
            }
            float* p = os + (t * 16 + n) * kPix + px_st;
            if (full4) {
                *reinterpret_cast<float4*>(p) = make_float4(h[t][0], h[t][1], h[t][2], h[t][3]);
            } else {
                #pragma unroll
                for (int r = 0; r < 4; ++r)
                    if (px_st + r <= 61) p[r] = h[t][r];
            }
            if (s == kS - 1) {
                float* pf = outf + (t * 16 + n) * kPix + py * kWP + px_st;
                if (full4) {
                    *reinterpret_cast<float4*>(pf) = make_float4(h[t][0], h[t][1], h[t][2], h[t][3]);
                } else {
                    #pragma unroll
                    for (int r = 0; r < 4; ++r)
                        if (px_st + r <= 61) pf[r] = h[t][r];
                }
            }
        }
    }
}

} // namespace

extern "C" void kernel_launch(void* const* d_in, const int* in_sizes, int n_in,
                              void* d_out, int out_size, void* d_ws, size_t ws_size,
                              hipStream_t stream)
{
    const float* x  = (const float*)d_in[0];
    const float* Wt = (const float*)d_in[1];
    const float* b  = (const float*)d_in[2];
    float* out = (float*)d_out;

    // workspace layout: Wk (64*160 bf16 = 20 KB, padded to 32 KB) | x_t (64 MB)
    __hip_bfloat16* wk = (__hip_bfloat16*)d_ws;
    __hip_bfloat16* xt = (__hip_bfloat16*)((char*)d_ws + 32768);

    reorder_w<<<dim3((64 * kKpad + 255) / 256), dim3(256), 0, stream>>>(Wt, wk);
    transpose_x<<<dim3(kB * kS * kH * kW / 256), dim3(256), 0, stream>>>(x, xt);
    conv_gru_mfma<<<dim3(kHP, kB), dim3(256), 0, stream>>>(xt, wk, b, out);
}